// Round 2
// baseline (973.622 us; speedup 1.0000x reference)
//
#include <hip/hip_runtime.h>
#include <math.h>

#define T_TOKENS 32768
#define HIDDEN   4096
#define NEXP     128
#define TM       32            // tokens per block
#define KC       64            // k-chunk
#define XS_STRIDE 68           // 64 + 4 pad (keeps 16B alignment, breaks bank aliasing)
#define SC_STRIDE 129          // 128 + 1 pad for routing-phase LDS

// smem (floats): GEMM phase needs 32*68 + 64*128 = 10368; routing needs 2*32*129 = 8256
#define SMEM_FLOATS 10368

__global__ __launch_bounds__(256, 3) void glm4_router_kernel(
    const float* __restrict__ x, const float* __restrict__ w,
    const float* __restrict__ bias, float* __restrict__ out)
{
    __shared__ float smem[SMEM_FLOATS];
    float* xs = smem;                    // [TM][XS_STRIDE]
    float* ws = smem + TM * XS_STRIDE;   // [KC][NEXP] (k-major, transposed from global)

    const int tid = threadIdx.x;
    const int tg  = tid >> 5;            // 0..7  -> tokens 4*tg .. 4*tg+3
    const int eg  = tid & 31;            // 0..31 -> experts 4*eg .. 4*eg+3
    const int tok_base = blockIdx.x * TM;

    // fp64 accumulators: near-exact logits so ranking matches the np/jax
    // fp32 reference (whose own GEMM error ~1e-6 is the only residual noise).
    double acc[4][4];
#pragma unroll
    for (int i = 0; i < 4; ++i)
#pragma unroll
        for (int j = 0; j < 4; ++j) acc[i][j] = 0.0;

    for (int k0 = 0; k0 < HIDDEN; k0 += KC) {
        // ---- stage x tile: [32 tokens][64 k] -> xs[tok][k] ----
        {
            const int tok  = tid >> 3;       // 0..31
            const int part = tid & 7;        // 0..7, each covers 8 consecutive k
            const float* src = x + (size_t)(tok_base + tok) * HIDDEN + k0 + part * 8;
            float4 a = *(const float4*)(src);
            float4 b = *(const float4*)(src + 4);
            float* dst = xs + tok * XS_STRIDE + part * 8;
            *(float4*)(dst)     = a;
            *(float4*)(dst + 4) = b;
        }
        // ---- stage w tile transposed: global w[e][k] -> ws[k][e] ----
        {
            const int e    = tid >> 1;       // 0..127
            const int half = tid & 1;        // 0..1, 32 k each
            const float* src = w + (size_t)e * HIDDEN + k0 + half * 32;
#pragma unroll
            for (int j = 0; j < 8; ++j) {
                float4 v = *(const float4*)(src + 4 * j);
                const int kk = half * 32 + 4 * j;
                ws[(kk + 0) * NEXP + e] = v.x;
                ws[(kk + 1) * NEXP + e] = v.y;
                ws[(kk + 2) * NEXP + e] = v.z;
                ws[(kk + 3) * NEXP + e] = v.w;
            }
        }
        __syncthreads();

        // ---- compute: 4 tokens x 4 experts per thread, fp64 accumulate ----
#pragma unroll 2
        for (int k4 = 0; k4 < KC; k4 += 4) {
            float4 xv[4], wv[4];
#pragma unroll
            for (int i = 0; i < 4; ++i)
                xv[i] = *(const float4*)(xs + (4 * tg + i) * XS_STRIDE + k4);
#pragma unroll
            for (int kk = 0; kk < 4; ++kk)
                wv[kk] = *(const float4*)(ws + (k4 + kk) * NEXP + 4 * eg);
#pragma unroll
            for (int kk = 0; kk < 4; ++kk) {
                const double wd0 = (double)wv[kk].x;
                const double wd1 = (double)wv[kk].y;
                const double wd2 = (double)wv[kk].z;
                const double wd3 = (double)wv[kk].w;
#pragma unroll
                for (int i = 0; i < 4; ++i) {
                    const double xd = (double)((const float*)&xv[i])[kk];
                    acc[i][0] = fma(xd, wd0, acc[i][0]);
                    acc[i][1] = fma(xd, wd1, acc[i][1]);
                    acc[i][2] = fma(xd, wd2, acc[i][2]);
                    acc[i][3] = fma(xd, wd3, acc[i][3]);
                }
            }
        }
        __syncthreads();
    }

    // ---- scores into LDS (overlay on smem; all tile reads are done) ----
    // Pipeline mimics the reference's fp32 value chain:
    //   logit_f32 = round_f32(exact logit)
    //   s_f32     = round_f32(sigmoid_f64(logit_f32))   (correctly rounded)
    //   biased    = s_f32 + bias_f32                     (fp32 add, as in ref)
    float* sc  = smem;                    // [TM][SC_STRIDE] sigmoid + bias (fp32)
    float* raw = smem + TM * SC_STRIDE;   // [TM][SC_STRIDE] raw sigmoid (fp32)
#pragma unroll
    for (int i = 0; i < 4; ++i) {
#pragma unroll
        for (int j = 0; j < 4; ++j) {
            const int tok = 4 * tg + i;
            const int e   = 4 * eg + j;
            const float lg = (float)acc[i][j];
            const double ev = exp(-(double)lg);
            const float s  = (float)(1.0 / (1.0 + ev));
            sc[tok * SC_STRIDE + e]  = s + bias[e];
            raw[tok * SC_STRIDE + e] = s;
        }
    }
    __syncthreads();

    // ---- routing: one lane per token (lanes 0..31 of wave 0), pure fp32 ----
    if (tid < TM) {
        const int tok = tid;
        const float* scp  = sc  + tok * SC_STRIDE;
        const float* rawp = raw + tok * SC_STRIDE;

        // group scores: sum of top-2 biased scores within each group of 16
        float gsc[8];
#pragma unroll
        for (int g = 0; g < 8; ++g) {
            float m1 = -1e30f, m2 = -1e30f;
#pragma unroll
            for (int j = 0; j < 16; ++j) {
                const float v = scp[g * 16 + j];
                if (v > m1) { m2 = m1; m1 = v; }
                else if (v > m2) { m2 = v; }
            }
            gsc[g] = m1 + m2;
        }

        // top-4 groups (ties -> lower index, matching jax.lax.top_k)
        unsigned gmask = 0;
#pragma unroll
        for (int p = 0; p < 4; ++p) {
            float best = -1e30f; int bi = 0;
#pragma unroll
            for (int g = 0; g < 8; ++g) {
                const bool taken = (gmask >> g) & 1u;
                if (!taken && gsc[g] > best) { best = gsc[g]; bi = g; }
            }
            gmask |= 1u << bi;
        }

        // top-8 experts over masked scores (masked entries count as 0.0,
        // exactly like jnp.where(mask>0, scores_for_choice, 0.0))
        unsigned long long chosen0 = 0ull, chosen1 = 0ull;
        int   idxs[8];
        float wts[8];
#pragma unroll
        for (int p = 0; p < 8; ++p) {
            float best = -1e30f; int bi = 0;
            for (int e = 0; e < NEXP; ++e) {
                const bool sel = (gmask >> (e >> 4)) & 1u;
                const float v = sel ? scp[e] : 0.0f;
                const bool ch = (e < 64) ? ((chosen0 >> e) & 1ull)
                                         : ((chosen1 >> (e - 64)) & 1ull);
                if (!ch && v > best) { best = v; bi = e; }
            }
            if (bi < 64) chosen0 |= 1ull << bi; else chosen1 |= 1ull << (bi - 64);
            idxs[p] = bi;
            wts[p] = rawp[bi];
        }

        // denom = sum(topk_weights) + 1e-20, then fp32 division (as in ref)
        float denom = 0.0f;
#pragma unroll
        for (int p = 0; p < 8; ++p) denom += wts[p];
        denom += 1e-20f;

        const size_t row = (size_t)(tok_base + tok) * 8;
        float* outI = out;
        float* outW = out + (size_t)T_TOKENS * 8;
#pragma unroll
        for (int p = 0; p < 8; ++p) {
            outI[row + p] = (float)idxs[p];
            outW[row + p] = wts[p] / denom;
        }
    }
}

extern "C" void kernel_launch(void* const* d_in, const int* in_sizes, int n_in,
                              void* d_out, int out_size, void* d_ws, size_t ws_size,
                              hipStream_t stream) {
    const float* x    = (const float*)d_in[0];  // [32768, 4096]
    const float* w    = (const float*)d_in[1];  // [128, 4096]
    const float* bias = (const float*)d_in[2];  // [128]
    float* out = (float*)d_out;                 // [32768*8 idx-as-float][32768*8 weights]

    dim3 grid(T_TOKENS / TM);
    glm4_router_kernel<<<grid, 256, 0, stream>>>(x, w, bias, out);
}

// Round 3
// 374.130 us; speedup vs baseline: 2.6024x; 2.6024x over previous
//
#include <hip/hip_runtime.h>
#include <math.h>

#define T_TOKENS 32768
#define HIDDEN   4096
#define NEXP     128
#define TM       64            // tokens per block
#define BK       64            // k per stage
#define A_PLANE  (TM * BK)     // 4096 shorts per x-plane
#define B_PLANE  (NEXP * BK)   // 8192 shorts per w-plane
#define B_BASE   (3 * A_PLANE) // 12288
#define LDS_SHORTS (B_BASE + 3 * B_PLANE)   // 36864 shorts = 72 KiB
#define SC_STRIDE 129

typedef short bf16x8 __attribute__((ext_vector_type(8)));
typedef short bf16x4 __attribute__((ext_vector_type(4)));
typedef float f32x4  __attribute__((ext_vector_type(4)));

__device__ __forceinline__ unsigned short f2bf(float f) {
    unsigned u = __float_as_uint(f);
    u += 0x7FFF + ((u >> 16) & 1);          // round-to-nearest-even
    return (unsigned short)(u >> 16);
}
__device__ __forceinline__ float bf2f(unsigned short h) {
    return __uint_as_float(((unsigned)h) << 16);
}
// 3-term bf16 cascade: x = b0 + b1 + b2 + delta, |delta| <= 2^-27 |x|
__device__ __forceinline__ void split3(float x, unsigned short& b0,
                                       unsigned short& b1, unsigned short& b2) {
    b0 = f2bf(x);
    float r1 = x - bf2f(b0);                // exact (Sterbenz)
    b1 = f2bf(r1);
    float r2 = r1 - bf2f(b1);               // exact
    b2 = f2bf(r2);
}
// XOR-swizzled LDS index (shorts). Keeps 8-short groups contiguous (16B reads ok),
// spreads row-column reads across banks (<=2-way, free per m136).
__device__ __forceinline__ int swz(int row, int k) {
    return row * BK + (k ^ ((row & 7) << 3));
}

__global__ __launch_bounds__(256, 2) void glm4_router_mfma(
    const float* __restrict__ x, const float* __restrict__ w,
    const float* __restrict__ bias, float* __restrict__ out)
{
    __shared__ __align__(16) short lds[LDS_SHORTS];

    const int tid  = threadIdx.x;
    const int wid  = tid >> 6;
    const int lane = tid & 63;
    const int wrow = (wid & 1) * 32;        // token-rows 0 / 32
    const int wcol = (wid >> 1) * 64;       // experts 0 / 64
    const int frow = lane & 15;
    const int fk   = (lane >> 4) * 8;
    const int tok_base = blockIdx.x * TM;

    f32x4 mainA[2][4];     // x0*w0, zeroed every K=128 chunk
    f32x4 corr[2][4];      // 5 correction products, full-K fp32
    double accd[2][4][4];  // fp64 running main sum
#pragma unroll
    for (int r = 0; r < 2; ++r)
#pragma unroll
        for (int c = 0; c < 4; ++c) {
            mainA[r][c] = (f32x4){0.f, 0.f, 0.f, 0.f};
            corr[r][c]  = (f32x4){0.f, 0.f, 0.f, 0.f};
#pragma unroll
            for (int v = 0; v < 4; ++v) accd[r][c][v] = 0.0;
        }

    for (int s = 0; s < HIDDEN / BK; ++s) {
        const int k0 = s * BK;
        if (s) __syncthreads();             // previous tile fully consumed

        // ---- stage x: 64 tok x 64 k, split to 3 bf16 planes ----
        {
            const float* xblk = x + (size_t)tok_base * HIDDEN + k0;
#pragma unroll
            for (int i = 0; i < 4; ++i) {
                const int g   = tid + 256 * i;
                const int row = g >> 4, c4 = g & 15;
                float4 v = *(const float4*)(xblk + (size_t)row * HIDDEN + c4 * 4);
                unsigned short h0[4], h1[4], h2[4];
                split3(v.x, h0[0], h1[0], h2[0]);
                split3(v.y, h0[1], h1[1], h2[1]);
                split3(v.z, h0[2], h1[2], h2[2]);
                split3(v.w, h0[3], h1[3], h2[3]);
                const int base = swz(row, c4 * 4);
                *(bf16x4*)(&lds[0 * A_PLANE + base]) =
                    (bf16x4){(short)h0[0], (short)h0[1], (short)h0[2], (short)h0[3]};
                *(bf16x4*)(&lds[1 * A_PLANE + base]) =
                    (bf16x4){(short)h1[0], (short)h1[1], (short)h1[2], (short)h1[3]};
                *(bf16x4*)(&lds[2 * A_PLANE + base]) =
                    (bf16x4){(short)h2[0], (short)h2[1], (short)h2[2], (short)h2[3]};
            }
        }
        // ---- stage w: 128 exp x 64 k, split to 3 bf16 planes ----
        {
#pragma unroll
            for (int i = 0; i < 8; ++i) {
                const int g  = tid + 256 * i;
                const int e  = g >> 4, k4 = g & 15;
                float4 v = *(const float4*)(w + (size_t)e * HIDDEN + k0 + k4 * 4);
                unsigned short h0[4], h1[4], h2[4];
                split3(v.x, h0[0], h1[0], h2[0]);
                split3(v.y, h0[1], h1[1], h2[1]);
                split3(v.z, h0[2], h1[2], h2[2]);
                split3(v.w, h0[3], h1[3], h2[3]);
                const int base = B_BASE + swz(e, k4 * 4);
                *(bf16x4*)(&lds[0 * B_PLANE + base]) =
                    (bf16x4){(short)h0[0], (short)h0[1], (short)h0[2], (short)h0[3]};
                *(bf16x4*)(&lds[1 * B_PLANE + base]) =
                    (bf16x4){(short)h1[0], (short)h1[1], (short)h1[2], (short)h1[3]};
                *(bf16x4*)(&lds[2 * B_PLANE + base]) =
                    (bf16x4){(short)h2[0], (short)h2[1], (short)h2[2], (short)h2[3]};
            }
        }
        __syncthreads();

        // ---- compute: 2 k-steps of K=32 ----
#pragma unroll
        for (int kk = 0; kk < 2; ++kk) {
            const int kb = kk * 32 + fk;
            bf16x8 A[3][2], B[3][4];
#pragma unroll
            for (int p = 0; p < 3; ++p)
#pragma unroll
                for (int r = 0; r < 2; ++r)
                    A[p][r] = *(const bf16x8*)(&lds[p * A_PLANE + swz(wrow + r * 16 + frow, kb)]);
#pragma unroll
            for (int p = 0; p < 3; ++p)
#pragma unroll
                for (int c = 0; c < 4; ++c)
                    B[p][c] = *(const bf16x8*)(&lds[B_BASE + p * B_PLANE + swz(wcol + c * 16 + frow, kb)]);
#pragma unroll
            for (int r = 0; r < 2; ++r)
#pragma unroll
                for (int c = 0; c < 4; ++c) {
                    mainA[r][c] = __builtin_amdgcn_mfma_f32_16x16x32_bf16(A[0][r], B[0][c], mainA[r][c], 0, 0, 0);
                    corr[r][c]  = __builtin_amdgcn_mfma_f32_16x16x32_bf16(A[0][r], B[1][c], corr[r][c], 0, 0, 0);
                    corr[r][c]  = __builtin_amdgcn_mfma_f32_16x16x32_bf16(A[1][r], B[0][c], corr[r][c], 0, 0, 0);
                    corr[r][c]  = __builtin_amdgcn_mfma_f32_16x16x32_bf16(A[0][r], B[2][c], corr[r][c], 0, 0, 0);
                    corr[r][c]  = __builtin_amdgcn_mfma_f32_16x16x32_bf16(A[2][r], B[0][c], corr[r][c], 0, 0, 0);
                    corr[r][c]  = __builtin_amdgcn_mfma_f32_16x16x32_bf16(A[1][r], B[1][c], corr[r][c], 0, 0, 0);
                }
        }

        // ---- fold main into fp64 every K=128 (caps fp32 random walk at ~1.2e-7) ----
        if (s & 1) {
#pragma unroll
            for (int r = 0; r < 2; ++r)
#pragma unroll
                for (int c = 0; c < 4; ++c) {
#pragma unroll
                    for (int v = 0; v < 4; ++v) accd[r][c][v] += (double)mainA[r][c][v];
                    mainA[r][c] = (f32x4){0.f, 0.f, 0.f, 0.f};
                }
        }
    }

    // ---- epilogue: logits -> scores into LDS overlay ----
    __syncthreads();
    float* sc  = (float*)lds;                    // [64][129]
    float* raw = sc + TM * SC_STRIDE;            // [64][129]
#pragma unroll
    for (int r = 0; r < 2; ++r)
#pragma unroll
        for (int c = 0; c < 4; ++c) {
#pragma unroll
            for (int v = 0; v < 4; ++v) {
                const int tokl = wrow + r * 16 + (lane >> 4) * 4 + v;
                const int e    = wcol + c * 16 + (lane & 15);
                const float lg = (float)(accd[r][c][v] + (double)corr[r][c][v]);
                const float sg = (float)(1.0 / (1.0 + exp(-(double)lg)));
                sc[tokl * SC_STRIDE + e]  = sg + bias[e];
                raw[tokl * SC_STRIDE + e] = sg;
            }
        }
    __syncthreads();

    // ---- routing: one lane per token (wave 0) — verified round-2 logic ----
    if (tid < TM) {
        const float* scp  = sc  + tid * SC_STRIDE;
        const float* rawp = raw + tid * SC_STRIDE;

        float gsc[8];
#pragma unroll
        for (int g = 0; g < 8; ++g) {
            float m1 = -1e30f, m2 = -1e30f;
#pragma unroll
            for (int j = 0; j < 16; ++j) {
                const float v = scp[g * 16 + j];
                if (v > m1) { m2 = m1; m1 = v; }
                else if (v > m2) { m2 = v; }
            }
            gsc[g] = m1 + m2;
        }

        unsigned gmask = 0;
#pragma unroll
        for (int p = 0; p < 4; ++p) {
            float best = -1e30f; int bi = 0;
#pragma unroll
            for (int g = 0; g < 8; ++g) {
                const bool taken = (gmask >> g) & 1u;
                if (!taken && gsc[g] > best) { best = gsc[g]; bi = g; }
            }
            gmask |= 1u << bi;
        }

        unsigned long long chosen0 = 0ull, chosen1 = 0ull;
        int   idxs[8];
        float wts[8];
#pragma unroll
        for (int p = 0; p < 8; ++p) {
            float best = -1e30f; int bi = 0;
            for (int e = 0; e < NEXP; ++e) {
                const bool sel = (gmask >> (e >> 4)) & 1u;
                const float v = sel ? scp[e] : 0.0f;
                const bool ch = (e < 64) ? ((chosen0 >> e) & 1ull)
                                         : ((chosen1 >> (e - 64)) & 1ull);
                if (!ch && v > best) { best = v; bi = e; }
            }
            if (bi < 64) chosen0 |= 1ull << bi; else chosen1 |= 1ull << (bi - 64);
            idxs[p] = bi;
            wts[p] = rawp[bi];
        }

        float denom = 0.0f;
#pragma unroll
        for (int p = 0; p < 8; ++p) denom += wts[p];
        denom += 1e-20f;

        const size_t row = (size_t)(tok_base + tid) * 8;
        float* outI = out;
        float* outW = out + (size_t)T_TOKENS * 8;
#pragma unroll
        for (int p = 0; p < 8; ++p) {
            outI[row + p] = (float)idxs[p];
            outW[row + p] = wts[p] / denom;
        }
    }
}

extern "C" void kernel_launch(void* const* d_in, const int* in_sizes, int n_in,
                              void* d_out, int out_size, void* d_ws, size_t ws_size,
                              hipStream_t stream) {
    const float* x    = (const float*)d_in[0];  // [32768, 4096]
    const float* w    = (const float*)d_in[1];  // [128, 4096]
    const float* bias = (const float*)d_in[2];  // [128]
    float* out = (float*)d_out;                 // [idx-as-float | weights]

    dim3 grid(T_TOKENS / TM);
    glm4_router_mfma<<<grid, 256, 0, stream>>>(x, w, bias, out);
}

// Round 4
// 371.813 us; speedup vs baseline: 2.6186x; 1.0062x over previous
//
#include <hip/hip_runtime.h>
#include <math.h>

#define T_TOKENS 32768
#define HIDDEN   4096
#define NEXP     128
#define TM       64            // tokens per block
#define BK       64            // k per stage
#define A_PLANE  (TM * BK)     // 4096 shorts per x-plane
#define B_PLANE  (NEXP * BK)   // 8192 shorts per w-plane
#define B_BASE   (3 * A_PLANE) // 12288
#define LDS_SHORTS (B_BASE + 3 * B_PLANE)   // 36864 shorts = 72 KiB
#define SC_STRIDE 129

typedef short bf16x8 __attribute__((ext_vector_type(8)));
typedef short bf16x4 __attribute__((ext_vector_type(4)));
typedef float f32x4  __attribute__((ext_vector_type(4)));

__device__ __forceinline__ unsigned short f2bf(float f) {
    unsigned u = __float_as_uint(f);
    u += 0x7FFF + ((u >> 16) & 1);          // round-to-nearest-even
    return (unsigned short)(u >> 16);
}
__device__ __forceinline__ float bf2f(unsigned short h) {
    return __uint_as_float(((unsigned)h) << 16);
}
// 3-term bf16 cascade: x = b0 + b1 + b2 + delta, |delta| <= 2^-27 |x|
__device__ __forceinline__ void split3(float x, unsigned short& b0,
                                       unsigned short& b1, unsigned short& b2) {
    b0 = f2bf(x);
    float r1 = x - bf2f(b0);                // exact (Sterbenz)
    b1 = f2bf(r1);
    float r2 = r1 - bf2f(b1);               // exact
    b2 = f2bf(r2);
}
// XOR-swizzled LDS index (shorts). Keeps 8-short groups contiguous (16B reads ok),
// spreads row-column reads across banks (<=2-way, free per m136).
__device__ __forceinline__ int swz(int row, int k) {
    return row * BK + (k ^ ((row & 7) << 3));
}

__global__ __launch_bounds__(256, 2) void glm4_router_mfma(
    const float* __restrict__ x, const float* __restrict__ w,
    const float* __restrict__ bias, float* __restrict__ out)
{
    __shared__ __align__(16) short lds[LDS_SHORTS];

    const int tid  = threadIdx.x;
    const int wid  = tid >> 6;
    const int lane = tid & 63;
    const int wrow = (wid & 1) * 32;        // token-rows 0 / 32
    const int wcol = (wid >> 1) * 64;       // experts 0 / 64
    const int frow = lane & 15;
    const int fk   = (lane >> 4) * 8;
    const int tok_base = blockIdx.x * TM;

    f32x4 mainA[2][4];     // x0*w0, zeroed every K=128 chunk
    f32x4 corr[2][4];      // 5 correction products, full-K fp32
    double accd[2][4][4];  // fp64 running main sum
#pragma unroll
    for (int r = 0; r < 2; ++r)
#pragma unroll
        for (int c = 0; c < 4; ++c) {
            mainA[r][c] = (f32x4){0.f, 0.f, 0.f, 0.f};
            corr[r][c]  = (f32x4){0.f, 0.f, 0.f, 0.f};
#pragma unroll
            for (int v = 0; v < 4; ++v) accd[r][c][v] = 0.0;
        }

    for (int s = 0; s < HIDDEN / BK; ++s) {
        const int k0 = s * BK;
        if (s) __syncthreads();             // previous tile fully consumed

        // ---- stage x: 64 tok x 64 k, split to 3 bf16 planes ----
        {
            const float* xblk = x + (size_t)tok_base * HIDDEN + k0;
#pragma unroll
            for (int i = 0; i < 4; ++i) {
                const int g   = tid + 256 * i;
                const int row = g >> 4, c4 = g & 15;
                float4 v = *(const float4*)(xblk + (size_t)row * HIDDEN + c4 * 4);
                unsigned short h0[4], h1[4], h2[4];
                split3(v.x, h0[0], h1[0], h2[0]);
                split3(v.y, h0[1], h1[1], h2[1]);
                split3(v.z, h0[2], h1[2], h2[2]);
                split3(v.w, h0[3], h1[3], h2[3]);
                const int base = swz(row, c4 * 4);
                *(bf16x4*)(&lds[0 * A_PLANE + base]) =
                    (bf16x4){(short)h0[0], (short)h0[1], (short)h0[2], (short)h0[3]};
                *(bf16x4*)(&lds[1 * A_PLANE + base]) =
                    (bf16x4){(short)h1[0], (short)h1[1], (short)h1[2], (short)h1[3]};
                *(bf16x4*)(&lds[2 * A_PLANE + base]) =
                    (bf16x4){(short)h2[0], (short)h2[1], (short)h2[2], (short)h2[3]};
            }
        }
        // ---- stage w: 128 exp x 64 k, split to 3 bf16 planes ----
        {
#pragma unroll
            for (int i = 0; i < 8; ++i) {
                const int g  = tid + 256 * i;
                const int e  = g >> 4, k4 = g & 15;
                float4 v = *(const float4*)(w + (size_t)e * HIDDEN + k0 + k4 * 4);
                unsigned short h0[4], h1[4], h2[4];
                split3(v.x, h0[0], h1[0], h2[0]);
                split3(v.y, h0[1], h1[1], h2[1]);
                split3(v.z, h0[2], h1[2], h2[2]);
                split3(v.w, h0[3], h1[3], h2[3]);
                const int base = B_BASE + swz(e, k4 * 4);
                *(bf16x4*)(&lds[0 * B_PLANE + base]) =
                    (bf16x4){(short)h0[0], (short)h0[1], (short)h0[2], (short)h0[3]};
                *(bf16x4*)(&lds[1 * B_PLANE + base]) =
                    (bf16x4){(short)h1[0], (short)h1[1], (short)h1[2], (short)h1[3]};
                *(bf16x4*)(&lds[2 * B_PLANE + base]) =
                    (bf16x4){(short)h2[0], (short)h2[1], (short)h2[2], (short)h2[3]};
            }
        }
        __syncthreads();

        // ---- compute: 2 k-steps of K=32 ----
#pragma unroll
        for (int kk = 0; kk < 2; ++kk) {
            const int kb = kk * 32 + fk;
            bf16x8 A[3][2], B[3][4];
#pragma unroll
            for (int p = 0; p < 3; ++p)
#pragma unroll
                for (int r = 0; r < 2; ++r)
                    A[p][r] = *(const bf16x8*)(&lds[p * A_PLANE + swz(wrow + r * 16 + frow, kb)]);
#pragma unroll
            for (int p = 0; p < 3; ++p)
#pragma unroll
                for (int c = 0; c < 4; ++c)
                    B[p][c] = *(const bf16x8*)(&lds[B_BASE + p * B_PLANE + swz(wcol + c * 16 + frow, kb)]);
#pragma unroll
            for (int r = 0; r < 2; ++r)
#pragma unroll
                for (int c = 0; c < 4; ++c) {
                    mainA[r][c] = __builtin_amdgcn_mfma_f32_16x16x32_bf16(A[0][r], B[0][c], mainA[r][c], 0, 0, 0);
                    corr[r][c]  = __builtin_amdgcn_mfma_f32_16x16x32_bf16(A[0][r], B[1][c], corr[r][c], 0, 0, 0);
                    corr[r][c]  = __builtin_amdgcn_mfma_f32_16x16x32_bf16(A[1][r], B[0][c], corr[r][c], 0, 0, 0);
                    corr[r][c]  = __builtin_amdgcn_mfma_f32_16x16x32_bf16(A[0][r], B[2][c], corr[r][c], 0, 0, 0);
                    corr[r][c]  = __builtin_amdgcn_mfma_f32_16x16x32_bf16(A[2][r], B[0][c], corr[r][c], 0, 0, 0);
                    corr[r][c]  = __builtin_amdgcn_mfma_f32_16x16x32_bf16(A[1][r], B[1][c], corr[r][c], 0, 0, 0);
                }
        }

        // ---- fold main into fp64 every K=128 (caps fp32 random walk at ~1.2e-7) ----
        if (s & 1) {
#pragma unroll
            for (int r = 0; r < 2; ++r)
#pragma unroll
                for (int c = 0; c < 4; ++c) {
#pragma unroll
                    for (int v = 0; v < 4; ++v) accd[r][c][v] += (double)mainA[r][c][v];
                    mainA[r][c] = (f32x4){0.f, 0.f, 0.f, 0.f};
                }
        }
    }

    // ---- epilogue: logits -> scores into LDS overlay ----
    __syncthreads();
    float* sc  = (float*)lds;                    // [64][129]
    float* raw = sc + TM * SC_STRIDE;            // [64][129]
#pragma unroll
    for (int r = 0; r < 2; ++r)
#pragma unroll
        for (int c = 0; c < 4; ++c) {
#pragma unroll
            for (int v = 0; v < 4; ++v) {
                const int tokl = wrow + r * 16 + (lane >> 4) * 4 + v;
                const int e    = wcol + c * 16 + (lane & 15);
                const float lg = (float)(accd[r][c][v] + (double)corr[r][c][v]);
                const float sg = (float)(1.0 / (1.0 + exp(-(double)lg)));
                sc[tokl * SC_STRIDE + e]  = sg + bias[e];
                raw[tokl * SC_STRIDE + e] = sg;
            }
        }
    __syncthreads();

    // ---- routing: one lane per token (wave 0) — verified round-2 logic ----
    if (tid < TM) {
        const float* scp  = sc  + tid * SC_STRIDE;
        const float* rawp = raw + tid * SC_STRIDE;

        float gsc[8];
#pragma unroll
        for (int g = 0; g < 8; ++g) {
            float m1 = -1e30f, m2 = -1e30f;
#pragma unroll
            for (int j = 0; j < 16; ++j) {
                const float v = scp[g * 16 + j];
                if (v > m1) { m2 = m1; m1 = v; }
                else if (v > m2) { m2 = v; }
            }
            gsc[g] = m1 + m2;
        }

        unsigned gmask = 0;
#pragma unroll
        for (int p = 0; p < 4; ++p) {
            float best = -1e30f; int bi = 0;
#pragma unroll
            for (int g = 0; g < 8; ++g) {
                const bool taken = (gmask >> g) & 1u;
                if (!taken && gsc[g] > best) { best = gsc[g]; bi = g; }
            }
            gmask |= 1u << bi;
        }

        unsigned long long chosen0 = 0ull, chosen1 = 0ull;
        int   idxs[8];
        float wts[8];
#pragma unroll
        for (int p = 0; p < 8; ++p) {
            float best = -1e30f; int bi = 0;
            for (int e = 0; e < NEXP; ++e) {
                const bool sel = (gmask >> (e >> 4)) & 1u;
                const float v = sel ? scp[e] : 0.0f;
                const bool ch = (e < 64) ? ((chosen0 >> e) & 1ull)
                                         : ((chosen1 >> (e - 64)) & 1ull);
                if (!ch && v > best) { best = v; bi = e; }
            }
            if (bi < 64) chosen0 |= 1ull << bi; else chosen1 |= 1ull << (bi - 64);
            idxs[p] = bi;
            wts[p] = rawp[bi];
        }

        float denom = 0.0f;
#pragma unroll
        for (int p = 0; p < 8; ++p) denom += wts[p];
        denom += 1e-20f;

        const size_t row = (size_t)(tok_base + tid) * 8;
        float* outI = out;
        float* outW = out + (size_t)T_TOKENS * 8;
#pragma unroll
        for (int p = 0; p < 8; ++p) {
            outI[row + p] = (float)idxs[p];
            outW[row + p] = wts[p] / denom;
        }
    }
}

extern "C" void kernel_launch(void* const* d_in, const int* in_sizes, int n_in,
                              void* d_out, int out_size, void* d_ws, size_t ws_size,
                              hipStream_t stream) {
    const float* x    = (const float*)d_in[0];  // [32768, 4096]
    const float* w    = (const float*)d_in[1];  // [128, 4096]
    const float* bias = (const float*)d_in[2];  // [128]
    float* out = (float*)d_out;                 // [idx-as-float | weights]

    dim3 grid(T_TOKENS / TM);
    glm4_router_mfma<<<grid, 256, 0, stream>>>(x, w, bias, out);
}

// Round 5
// 315.913 us; speedup vs baseline: 3.0819x; 1.1769x over previous
//
#include <hip/hip_runtime.h>
#include <math.h>

#define T_TOKENS 32768
#define HIDDEN   4096
#define NEXP     128
#define TM       64            // tokens per block
#define BK       64            // k per stage
#define A_PLANE  (TM * BK)     // 4096 shorts per x-plane
#define B_PLANE  (NEXP * BK)   // 8192 shorts per w-plane
#define B_BASE   (3 * A_PLANE) // 12288
#define LDS_SHORTS (B_BASE + 3 * B_PLANE)   // 36864 shorts = 72 KiB
#define SC_STRIDE 129
#define WS_SHORTS ((size_t)3 * NEXP * HIDDEN)          // pre-split w: 3 MB
#define WS_BYTES  (WS_SHORTS * 2)

typedef short bf16x8 __attribute__((ext_vector_type(8)));
typedef short bf16x4 __attribute__((ext_vector_type(4)));
typedef float f32x4  __attribute__((ext_vector_type(4)));

__device__ __forceinline__ unsigned short f2bf(float f) {
    unsigned u = __float_as_uint(f);
    u += 0x7FFF + ((u >> 16) & 1);          // round-to-nearest-even
    return (unsigned short)(u >> 16);
}
__device__ __forceinline__ float bf2f(unsigned short h) {
    return __uint_as_float(((unsigned)h) << 16);
}
// 3-term bf16 cascade: x = b0 + b1 + b2 + delta, |delta| <= 2^-27 |x|
__device__ __forceinline__ void split3(float x, unsigned short& b0,
                                       unsigned short& b1, unsigned short& b2) {
    b0 = f2bf(x);
    float r1 = x - bf2f(b0);                // exact (Sterbenz)
    b1 = f2bf(r1);
    float r2 = r1 - bf2f(b1);               // exact
    b2 = f2bf(r2);
}
// XOR-swizzled LDS index (shorts); keeps 4/8-short groups contiguous,
// spreads column reads across banks.
__device__ __forceinline__ int swz(int row, int k) {
    return row * BK + (k ^ ((row & 7) << 3));
}

// ---- kernel 1: split w once into 3 bf16 planes, laid out per-stage and
// pre-swizzled so each stage's 48 KB chunk is a byte-exact image of the
// main kernel's B LDS region (linear global_load_lds copy). ----
// ws16 layout: [(s*3 + p) * NEXP*BK + swz(e, kin)]
__global__ __launch_bounds__(256) void presplit_w(
    const float* __restrict__ w, short* __restrict__ ws16)
{
    const int g  = blockIdx.x * 256 + threadIdx.x;   // 131072 total
    const int e  = g >> 10;                          // 0..127
    const int kq = (g & 1023) * 4;                   // 0..4092
    const int s   = kq >> 6;
    const int kin = kq & 63;
    float4 v = *(const float4*)(w + (size_t)e * HIDDEN + kq);
    unsigned short h0[4], h1[4], h2[4];
    split3(v.x, h0[0], h1[0], h2[0]);
    split3(v.y, h0[1], h1[1], h2[1]);
    split3(v.z, h0[2], h1[2], h2[2]);
    split3(v.w, h0[3], h1[3], h2[3]);
    const int base = swz(e, kin);                    // within one plane chunk
    short* c0 = ws16 + (size_t)(s * 3 + 0) * (NEXP * BK) + base;
    short* c1 = ws16 + (size_t)(s * 3 + 1) * (NEXP * BK) + base;
    short* c2 = ws16 + (size_t)(s * 3 + 2) * (NEXP * BK) + base;
    *(bf16x4*)c0 = (bf16x4){(short)h0[0], (short)h0[1], (short)h0[2], (short)h0[3]};
    *(bf16x4*)c1 = (bf16x4){(short)h1[0], (short)h1[1], (short)h1[2], (short)h1[3]};
    *(bf16x4*)c2 = (bf16x4){(short)h2[0], (short)h2[1], (short)h2[2], (short)h2[3]};
}

template <bool PRESPLIT>
__global__ __launch_bounds__(256, 2) void glm4_router_mfma(
    const float* __restrict__ x, const float* __restrict__ w,
    const short* __restrict__ wsplit,
    const float* __restrict__ bias, float* __restrict__ out)
{
    __shared__ __align__(16) short lds[LDS_SHORTS];

    const int tid  = threadIdx.x;
    const int wid  = tid >> 6;
    const int lane = tid & 63;
    const int wrow = (wid & 1) * 32;        // token-rows 0 / 32
    const int wcol = (wid >> 1) * 64;       // experts 0 / 64
    const int frow = lane & 15;
    const int fk   = (lane >> 4) * 8;
    const int tok_base = blockIdx.x * TM;

    f32x4 mainA[2][4];     // x0*w0, zeroed every K=128 chunk
    f32x4 corr[2][4];      // 5 correction products, full-K fp32
    double accd[2][4][4];  // fp64 running main sum
#pragma unroll
    for (int r = 0; r < 2; ++r)
#pragma unroll
        for (int c = 0; c < 4; ++c) {
            mainA[r][c] = (f32x4){0.f, 0.f, 0.f, 0.f};
            corr[r][c]  = (f32x4){0.f, 0.f, 0.f, 0.f};
#pragma unroll
            for (int v = 0; v < 4; ++v) accd[r][c][v] = 0.0;
        }

    for (int s = 0; s < HIDDEN / BK; ++s) {
        const int k0 = s * BK;
        if (s) __syncthreads();             // previous tile fully consumed

        // ---- stage w planes FIRST (loads fly under the A-split VALU) ----
        if (PRESPLIT) {
            // 48 KB linear copy: pre-split, pre-swizzled image in d_ws
            const char* gsrc = (const char*)(wsplit + (size_t)s * (3 * NEXP * BK)) + tid * 16;
            char* ldst = (char*)&lds[B_BASE] + tid * 16;
#pragma unroll
            for (int i = 0; i < 12; ++i) {
                __builtin_amdgcn_global_load_lds(
                    (const __attribute__((address_space(1))) unsigned*)(gsrc + i * 4096),
                    (__attribute__((address_space(3))) unsigned*)(ldst + i * 4096),
                    16, 0, 0);
            }
        } else {
#pragma unroll
            for (int i = 0; i < 8; ++i) {
                const int g  = tid + 256 * i;
                const int e  = g >> 4, k4 = g & 15;
                float4 v = *(const float4*)(w + (size_t)e * HIDDEN + k0 + k4 * 4);
                unsigned short h0[4], h1[4], h2[4];
                split3(v.x, h0[0], h1[0], h2[0]);
                split3(v.y, h0[1], h1[1], h2[1]);
                split3(v.z, h0[2], h1[2], h2[2]);
                split3(v.w, h0[3], h1[3], h2[3]);
                const int base = B_BASE + swz(e, k4 * 4);
                *(bf16x4*)(&lds[0 * B_PLANE + base]) =
                    (bf16x4){(short)h0[0], (short)h0[1], (short)h0[2], (short)h0[3]};
                *(bf16x4*)(&lds[1 * B_PLANE + base]) =
                    (bf16x4){(short)h1[0], (short)h1[1], (short)h1[2], (short)h1[3]};
                *(bf16x4*)(&lds[2 * B_PLANE + base]) =
                    (bf16x4){(short)h2[0], (short)h2[1], (short)h2[2], (short)h2[3]};
            }
        }

        // ---- stage x: 64 tok x 64 k, split to 3 bf16 planes ----
        {
            const float* xblk = x + (size_t)tok_base * HIDDEN + k0;
#pragma unroll
            for (int i = 0; i < 4; ++i) {
                const int g   = tid + 256 * i;
                const int row = g >> 4, c4 = g & 15;
                float4 v = *(const float4*)(xblk + (size_t)row * HIDDEN + c4 * 4);
                unsigned short h0[4], h1[4], h2[4];
                split3(v.x, h0[0], h1[0], h2[0]);
                split3(v.y, h0[1], h1[1], h2[1]);
                split3(v.z, h0[2], h1[2], h2[2]);
                split3(v.w, h0[3], h1[3], h2[3]);
                const int base = swz(row, c4 * 4);
                *(bf16x4*)(&lds[0 * A_PLANE + base]) =
                    (bf16x4){(short)h0[0], (short)h0[1], (short)h0[2], (short)h0[3]};
                *(bf16x4*)(&lds[1 * A_PLANE + base]) =
                    (bf16x4){(short)h1[0], (short)h1[1], (short)h1[2], (short)h1[3]};
                *(bf16x4*)(&lds[2 * A_PLANE + base]) =
                    (bf16x4){(short)h2[0], (short)h2[1], (short)h2[2], (short)h2[3]};
            }
        }
        __syncthreads();

        // ---- compute: 2 k-steps of K=32 ----
#pragma unroll
        for (int kk = 0; kk < 2; ++kk) {
            const int kb = kk * 32 + fk;
            bf16x8 A[3][2], B[3][4];
#pragma unroll
            for (int p = 0; p < 3; ++p)
#pragma unroll
                for (int r = 0; r < 2; ++r)
                    A[p][r] = *(const bf16x8*)(&lds[p * A_PLANE + swz(wrow + r * 16 + frow, kb)]);
#pragma unroll
            for (int p = 0; p < 3; ++p)
#pragma unroll
                for (int c = 0; c < 4; ++c)
                    B[p][c] = *(const bf16x8*)(&lds[B_BASE + p * B_PLANE + swz(wcol + c * 16 + frow, kb)]);
#pragma unroll
            for (int r = 0; r < 2; ++r)
#pragma unroll
                for (int c = 0; c < 4; ++c) {
                    mainA[r][c] = __builtin_amdgcn_mfma_f32_16x16x32_bf16(A[0][r], B[0][c], mainA[r][c], 0, 0, 0);
                    corr[r][c]  = __builtin_amdgcn_mfma_f32_16x16x32_bf16(A[0][r], B[1][c], corr[r][c], 0, 0, 0);
                    corr[r][c]  = __builtin_amdgcn_mfma_f32_16x16x32_bf16(A[1][r], B[0][c], corr[r][c], 0, 0, 0);
                    corr[r][c]  = __builtin_amdgcn_mfma_f32_16x16x32_bf16(A[0][r], B[2][c], corr[r][c], 0, 0, 0);
                    corr[r][c]  = __builtin_amdgcn_mfma_f32_16x16x32_bf16(A[2][r], B[0][c], corr[r][c], 0, 0, 0);
                    corr[r][c]  = __builtin_amdgcn_mfma_f32_16x16x32_bf16(A[1][r], B[1][c], corr[r][c], 0, 0, 0);
                }
        }

        // ---- fold main into fp64 every K=128 (caps fp32 random walk) ----
        if (s & 1) {
#pragma unroll
            for (int r = 0; r < 2; ++r)
#pragma unroll
                for (int c = 0; c < 4; ++c) {
#pragma unroll
                    for (int v = 0; v < 4; ++v) accd[r][c][v] += (double)mainA[r][c][v];
                    mainA[r][c] = (f32x4){0.f, 0.f, 0.f, 0.f};
                }
        }
    }

    // ---- epilogue: logits -> scores into LDS overlay ----
    __syncthreads();
    float* sc  = (float*)lds;                    // [64][129]
    float* raw = sc + TM * SC_STRIDE;            // [64][129]
#pragma unroll
    for (int r = 0; r < 2; ++r)
#pragma unroll
        for (int c = 0; c < 4; ++c) {
#pragma unroll
            for (int v = 0; v < 4; ++v) {
                const int tokl = wrow + r * 16 + (lane >> 4) * 4 + v;
                const int e    = wcol + c * 16 + (lane & 15);
                const float lg = (float)(accd[r][c][v] + (double)corr[r][c][v]);
                const float sg = (float)(1.0 / (1.0 + exp(-(double)lg)));
                sc[tokl * SC_STRIDE + e]  = sg + bias[e];
                raw[tokl * SC_STRIDE + e] = sg;
            }
        }
    __syncthreads();

    // ---- routing: one lane per token (wave 0) — verified round-2 logic ----
    if (tid < TM) {
        const float* scp  = sc  + tid * SC_STRIDE;
        const float* rawp = raw + tid * SC_STRIDE;

        float gsc[8];
#pragma unroll
        for (int g = 0; g < 8; ++g) {
            float m1 = -1e30f, m2 = -1e30f;
#pragma unroll
            for (int j = 0; j < 16; ++j) {
                const float v = scp[g * 16 + j];
                if (v > m1) { m2 = m1; m1 = v; }
                else if (v > m2) { m2 = v; }
            }
            gsc[g] = m1 + m2;
        }

        unsigned gmask = 0;
#pragma unroll
        for (int p = 0; p < 4; ++p) {
            float best = -1e30f; int bi = 0;
#pragma unroll
            for (int g = 0; g < 8; ++g) {
                const bool taken = (gmask >> g) & 1u;
                if (!taken && gsc[g] > best) { best = gsc[g]; bi = g; }
            }
            gmask |= 1u << bi;
        }

        unsigned long long chosen0 = 0ull, chosen1 = 0ull;
        int   idxs[8];
        float wts[8];
#pragma unroll
        for (int p = 0; p < 8; ++p) {
            float best = -1e30f; int bi = 0;
            for (int e = 0; e < NEXP; ++e) {
                const bool sel = (gmask >> (e >> 4)) & 1u;
                const float v = sel ? scp[e] : 0.0f;
                const bool ch = (e < 64) ? ((chosen0 >> e) & 1ull)
                                         : ((chosen1 >> (e - 64)) & 1ull);
                if (!ch && v > best) { best = v; bi = e; }
            }
            if (bi < 64) chosen0 |= 1ull << bi; else chosen1 |= 1ull << (bi - 64);
            idxs[p] = bi;
            wts[p] = rawp[bi];
        }

        float denom = 0.0f;
#pragma unroll
        for (int p = 0; p < 8; ++p) denom += wts[p];
        denom += 1e-20f;

        const size_t row = (size_t)(tok_base + tid) * 8;
        float* outI = out;
        float* outW = out + (size_t)T_TOKENS * 8;
#pragma unroll
        for (int p = 0; p < 8; ++p) {
            outI[row + p] = (float)idxs[p];
            outW[row + p] = wts[p] / denom;
        }
    }
}

extern "C" void kernel_launch(void* const* d_in, const int* in_sizes, int n_in,
                              void* d_out, int out_size, void* d_ws, size_t ws_size,
                              hipStream_t stream) {
    const float* x    = (const float*)d_in[0];  // [32768, 4096]
    const float* w    = (const float*)d_in[1];  // [128, 4096]
    const float* bias = (const float*)d_in[2];  // [128]
    float* out = (float*)d_out;                 // [idx-as-float | weights]

    dim3 grid(T_TOKENS / TM);
    if (ws_size >= WS_BYTES) {
        short* ws16 = (short*)d_ws;
        presplit_w<<<dim3(NEXP * HIDDEN / 4 / 256), 256, 0, stream>>>(w, ws16);
        glm4_router_mfma<true><<<grid, 256, 0, stream>>>(x, w, ws16, bias, out);
    } else {
        glm4_router_mfma<false><<<grid, 256, 0, stream>>>(x, w, nullptr, bias, out);
    }
}

// Round 6
// 290.229 us; speedup vs baseline: 3.3547x; 1.0885x over previous
//
#include <hip/hip_runtime.h>
#include <math.h>

#define T_TOKENS 32768
#define HIDDEN   4096
#define NEXP     128
#define TM       64
#define BK       32
#define NSTAGE   (HIDDEN / BK)            // 128
// fragment-major LDS (shorts): A = 3 planes * 4 tiles * 512, B = 3 * 8 * 512
#define A_SHORTS   (3 * 4 * 512)          // 6144  (12 KB)
#define B_BASE_SH  A_SHORTS
#define B_SHORTS   (3 * 8 * 512)          // 12288 (24 KB)
#define LDS_SHORTS (A_SHORTS + B_SHORTS)  // 18432 (36 KB)
#define A_PLANE_SH (4 * 512)              // 2048
#define B_PLANE_SH (8 * 512)              // 4096
#define SC_STRIDE  129
#define B_CHUNK_BYTES (B_SHORTS * 2)      // 24576 = 6 * 4096
#define WS_BYTES ((size_t)NSTAGE * B_CHUNK_BYTES)   // 3 MiB

typedef short bf16x8 __attribute__((ext_vector_type(8)));
typedef float f32x4  __attribute__((ext_vector_type(4)));

__device__ __forceinline__ unsigned short f2bf(float f) {
    unsigned u = __float_as_uint(f);
    u += 0x7FFF + ((u >> 16) & 1);          // round-to-nearest-even
    return (unsigned short)(u >> 16);
}
__device__ __forceinline__ float bf2f(unsigned short h) {
    return __uint_as_float(((unsigned)h) << 16);
}
// 3-term bf16 cascade: x = b0 + b1 + b2 + delta, |delta| <= 2^-27 |x|
__device__ __forceinline__ void split3(float x, unsigned short& b0,
                                       unsigned short& b1, unsigned short& b2) {
    b0 = f2bf(x);
    float r1 = x - bf2f(b0);                // exact (Sterbenz)
    b1 = f2bf(r1);
    float r2 = r1 - bf2f(b1);               // exact
    b2 = f2bf(r2);
}

// ---- kernel 1: split w into 3 bf16 planes in FRAGMENT-MAJOR order.
// For stage s, plane p, tile t (16 experts), lane l: the 8 bf16 values
// w[t*16 + (l&15)][s*32 + (l>>4)*8 + j], stored at
// ws16[((s*24 + p*8 + t)*64 + l)*8]. Each stage chunk = 24576 B, a
// byte-exact linear image of the main kernel's B LDS region.
__global__ __launch_bounds__(256) void presplit_w(
    const float* __restrict__ w, short* __restrict__ ws16)
{
    const int g = blockIdx.x * 256 + threadIdx.x;    // 65536 total
    const int l = g & 63;
    const int t = (g >> 6) & 7;
    const int s = g >> 9;                            // 0..127
    const int e  = t * 16 + (l & 15);
    const int kb = s * BK + ((l >> 4) & 3) * 8;
    const float* src = w + (size_t)e * HIDDEN + kb;
    float4 v0 = *(const float4*)(src);
    float4 v1 = *(const float4*)(src + 4);
    float vv[8] = {v0.x, v0.y, v0.z, v0.w, v1.x, v1.y, v1.z, v1.w};
    unsigned short h0[8], h1[8], h2[8];
#pragma unroll
    for (int j = 0; j < 8; ++j) split3(vv[j], h0[j], h1[j], h2[j]);
    const size_t base = ((size_t)s * 24 + t) * 64 + l;
    bf16x8 o0 = {(short)h0[0],(short)h0[1],(short)h0[2],(short)h0[3],
                 (short)h0[4],(short)h0[5],(short)h0[6],(short)h0[7]};
    bf16x8 o1 = {(short)h1[0],(short)h1[1],(short)h1[2],(short)h1[3],
                 (short)h1[4],(short)h1[5],(short)h1[6],(short)h1[7]};
    bf16x8 o2 = {(short)h2[0],(short)h2[1],(short)h2[2],(short)h2[3],
                 (short)h2[4],(short)h2[5],(short)h2[6],(short)h2[7]};
    *(bf16x8*)(ws16 + (base + 0 * 8 * 64) * 8) = o0;
    *(bf16x8*)(ws16 + (base + 1 * 8 * 64) * 8) = o1;
    *(bf16x8*)(ws16 + (base + 2 * 8 * 64) * 8) = o2;
}

__global__ __launch_bounds__(256, 3) void glm4_router_mfma(
    const float* __restrict__ x, const short* __restrict__ wsplit,
    const float* __restrict__ bias, float* __restrict__ out)
{
    __shared__ __align__(16) short lds[LDS_SHORTS];

    const int tid  = threadIdx.x;
    const int wid  = tid >> 6;
    const int lane = tid & 63;
    const int wrow = (wid & 1) * 32;        // token rows 0 / 32
    const int wcol = (wid >> 1) * 64;       // experts 0 / 64
    const int tok_base = blockIdx.x * TM;

    // A staging identity: thread -> (row, k-octet)
    const int arow = tid >> 2;              // 0..63
    const int aoct = tid & 3;               // 0..3
    const float* xrow = x + (size_t)(tok_base + arow) * HIDDEN + aoct * 8;
    // A fragment-major write offset (plane 0), plane stride = A_PLANE_SH
    const int awr = (((arow >> 4) * 64) + ((arow & 15) | (aoct << 4))) * 8;

    f32x4 acc[2][4];        // all 6 products, zeroed every K=128
    double accd[2][4][4];   // fp64 running sum
#pragma unroll
    for (int r = 0; r < 2; ++r)
#pragma unroll
        for (int c = 0; c < 4; ++c) {
            acc[r][c] = (f32x4){0.f, 0.f, 0.f, 0.f};
#pragma unroll
            for (int v = 0; v < 4; ++v) accd[r][c][v] = 0.0;
        }

    // prologue: load stage-0 x
    float4 c0 = *(const float4*)(xrow);
    float4 c1 = *(const float4*)(xrow + 4);

    for (int s = 0; s < NSTAGE; ++s) {
        if (s) __syncthreads();             // previous tile fully consumed

        // ---- B: 6 x 16B linear global_load_lds of the pre-split image ----
        {
            const char* gsrc = (const char*)wsplit + (size_t)s * B_CHUNK_BYTES + tid * 16;
            char* ldst = (char*)lds + B_BASE_SH * 2 + tid * 16;
#pragma unroll
            for (int i = 0; i < 6; ++i) {
                __builtin_amdgcn_global_load_lds(
                    (const __attribute__((address_space(1))) unsigned*)(gsrc + i * 4096),
                    (__attribute__((address_space(3))) unsigned*)(ldst + i * 4096),
                    16, 0, 0);
            }
        }

        // ---- prefetch next-stage x into registers ----
        float4 n0 = c0, n1 = c1;
        if (s + 1 < NSTAGE) {
            const float* nx = xrow + (size_t)(s + 1) * BK;
            n0 = *(const float4*)(nx);
            n1 = *(const float4*)(nx + 4);
        }

        // ---- split current x, write A fragments (conflict-free b128) ----
        {
            float vv[8] = {c0.x, c0.y, c0.z, c0.w, c1.x, c1.y, c1.z, c1.w};
            unsigned short h0[8], h1[8], h2[8];
#pragma unroll
            for (int j = 0; j < 8; ++j) split3(vv[j], h0[j], h1[j], h2[j]);
            bf16x8 o0 = {(short)h0[0],(short)h0[1],(short)h0[2],(short)h0[3],
                         (short)h0[4],(short)h0[5],(short)h0[6],(short)h0[7]};
            bf16x8 o1 = {(short)h1[0],(short)h1[1],(short)h1[2],(short)h1[3],
                         (short)h1[4],(short)h1[5],(short)h1[6],(short)h1[7]};
            bf16x8 o2 = {(short)h2[0],(short)h2[1],(short)h2[2],(short)h2[3],
                         (short)h2[4],(short)h2[5],(short)h2[6],(short)h2[7]};
            *(bf16x8*)(&lds[0 * A_PLANE_SH + awr]) = o0;
            *(bf16x8*)(&lds[1 * A_PLANE_SH + awr]) = o1;
            *(bf16x8*)(&lds[2 * A_PLANE_SH + awr]) = o2;
        }
        __syncthreads();

        // ---- compute: hoist A frags (6), loop c reading B frags (3 each) ----
        {
            bf16x8 A[3][2];
#pragma unroll
            for (int p = 0; p < 3; ++p)
#pragma unroll
                for (int r = 0; r < 2; ++r)
                    A[p][r] = *(const bf16x8*)(
                        &lds[p * A_PLANE_SH + (((wrow >> 4) + r) * 64 + lane) * 8]);
#pragma unroll
            for (int c = 0; c < 4; ++c) {
                bf16x8 B0 = *(const bf16x8*)(
                    &lds[B_BASE_SH + 0 * B_PLANE_SH + (((wcol >> 4) + c) * 64 + lane) * 8]);
                bf16x8 B1 = *(const bf16x8*)(
                    &lds[B_BASE_SH + 1 * B_PLANE_SH + (((wcol >> 4) + c) * 64 + lane) * 8]);
                bf16x8 B2 = *(const bf16x8*)(
                    &lds[B_BASE_SH + 2 * B_PLANE_SH + (((wcol >> 4) + c) * 64 + lane) * 8]);
#pragma unroll
                for (int r = 0; r < 2; ++r) {
                    acc[r][c] = __builtin_amdgcn_mfma_f32_16x16x32_bf16(A[0][r], B0, acc[r][c], 0, 0, 0);
                    acc[r][c] = __builtin_amdgcn_mfma_f32_16x16x32_bf16(A[0][r], B1, acc[r][c], 0, 0, 0);
                    acc[r][c] = __builtin_amdgcn_mfma_f32_16x16x32_bf16(A[1][r], B0, acc[r][c], 0, 0, 0);
                    acc[r][c] = __builtin_amdgcn_mfma_f32_16x16x32_bf16(A[0][r], B2, acc[r][c], 0, 0, 0);
                    acc[r][c] = __builtin_amdgcn_mfma_f32_16x16x32_bf16(A[2][r], B0, acc[r][c], 0, 0, 0);
                    acc[r][c] = __builtin_amdgcn_mfma_f32_16x16x32_bf16(A[1][r], B1, acc[r][c], 0, 0, 0);
                }
            }
        }

        // ---- fold into fp64 every K=128 (caps fp32 C-accum random walk) ----
        if ((s & 3) == 3) {
#pragma unroll
            for (int r = 0; r < 2; ++r)
#pragma unroll
                for (int c = 0; c < 4; ++c) {
#pragma unroll
                    for (int v = 0; v < 4; ++v) accd[r][c][v] += (double)acc[r][c][v];
                    acc[r][c] = (f32x4){0.f, 0.f, 0.f, 0.f};
                }
        }
        c0 = n0; c1 = n1;
    }

    // ---- epilogue: logits -> biased scores into LDS overlay (fp32) ----
    __syncthreads();
    float* sc = (float*)lds;                       // [64][129] = 33 KB
#pragma unroll
    for (int r = 0; r < 2; ++r)
#pragma unroll
        for (int c = 0; c < 4; ++c) {
#pragma unroll
            for (int v = 0; v < 4; ++v) {
                const int tokl = wrow + r * 16 + (lane >> 4) * 4 + v;
                const int e    = wcol + c * 16 + (lane & 15);
                const float lg = (float)accd[r][c][v];
                const float sg = (float)(1.0 / (1.0 + exp(-(double)lg)));
                sc[tokl * SC_STRIDE + e] = sg + bias[e];
            }
        }
    __syncthreads();

    // ---- routing: one lane per token (wave 0) — verified logic ----
    if (tid < TM) {
        const float* scp = sc + tid * SC_STRIDE;

        float gsc[8];
#pragma unroll
        for (int g = 0; g < 8; ++g) {
            float m1 = -1e30f, m2 = -1e30f;
#pragma unroll
            for (int j = 0; j < 16; ++j) {
                const float v = scp[g * 16 + j];
                if (v > m1) { m2 = m1; m1 = v; }
                else if (v > m2) { m2 = v; }
            }
            gsc[g] = m1 + m2;
        }

        unsigned gmask = 0;
#pragma unroll
        for (int p = 0; p < 4; ++p) {
            float best = -1e30f; int bi = 0;
#pragma unroll
            for (int g = 0; g < 8; ++g) {
                const bool taken = (gmask >> g) & 1u;
                if (!taken && gsc[g] > best) { best = gsc[g]; bi = g; }
            }
            gmask |= 1u << bi;
        }

        unsigned long long chosen0 = 0ull, chosen1 = 0ull;
        int   idxs[8];
        float wts[8];
#pragma unroll
        for (int p = 0; p < 8; ++p) {
            float best = -1e30f; int bi = 0;
            for (int e = 0; e < NEXP; ++e) {
                const bool sel = (gmask >> (e >> 4)) & 1u;
                const float v = sel ? scp[e] : 0.0f;
                const bool ch = (e < 64) ? ((chosen0 >> e) & 1ull)
                                         : ((chosen1 >> (e - 64)) & 1ull);
                if (!ch && v > best) { best = v; bi = e; }
            }
            if (bi < 64) chosen0 |= 1ull << bi; else chosen1 |= 1ull << (bi - 64);
            idxs[p] = bi;
            // raw sigmoid recovered: (s + b) - b, error <= ~1e-7 (weights
            // tolerance is ~1e-3; selection itself uses sc unchanged)
            wts[p] = scp[bi] - bias[bi];
        }

        float denom = 0.0f;
#pragma unroll
        for (int p = 0; p < 8; ++p) denom += wts[p];
        denom += 1e-20f;

        const size_t row = (size_t)(tok_base + tid) * 8;
        float* outI = out;
        float* outW = out + (size_t)T_TOKENS * 8;
#pragma unroll
        for (int p = 0; p < 8; ++p) {
            outI[row + p] = (float)idxs[p];
            outW[row + p] = wts[p] / denom;
        }
    }
}

extern "C" void kernel_launch(void* const* d_in, const int* in_sizes, int n_in,
                              void* d_out, int out_size, void* d_ws, size_t ws_size,
                              hipStream_t stream) {
    const float* x    = (const float*)d_in[0];  // [32768, 4096]
    const float* w    = (const float*)d_in[1];  // [128, 4096]
    const float* bias = (const float*)d_in[2];  // [128]
    float* out = (float*)d_out;                 // [idx-as-float | weights]
    short* ws16 = (short*)d_ws;                 // 3 MiB pre-split w image

    presplit_w<<<dim3(NSTAGE * 8 * 64 / 256), 256, 0, stream>>>(w, ws16);
    glm4_router_mfma<<<dim3(T_TOKENS / TM), 256, 0, stream>>>(x, ws16, bias, out);
}

// Round 7
// 285.726 us; speedup vs baseline: 3.4075x; 1.0158x over previous
//
#include <hip/hip_runtime.h>
#include <math.h>

#define T_TOKENS 32768
#define HIDDEN   4096
#define NEXP     128
#define TM       64
#define BK       32
#define NSTAGE   (HIDDEN / BK)            // 128
// fragment-major LDS (shorts): A = 3 planes * 4 tiles * 512, B = 3 * 8 * 512
#define A_SHORTS   (3 * 4 * 512)          // 6144  (12 KB)
#define B_BASE_SH  A_SHORTS
#define B_SHORTS   (3 * 8 * 512)          // 12288 (24 KB)
#define LDS_SHORTS (A_SHORTS + B_SHORTS)  // 18432 (36 KB)
#define A_PLANE_SH (4 * 512)              // 2048
#define B_PLANE_SH (8 * 512)              // 4096
#define SC_STRIDE  129
#define B_CHUNK_BYTES (B_SHORTS * 2)      // 24576 = 3 * 8192
#define WS_BYTES ((size_t)NSTAGE * B_CHUNK_BYTES)   // 3 MiB

typedef short bf16x8 __attribute__((ext_vector_type(8)));
typedef short bf16x4 __attribute__((ext_vector_type(4)));
typedef float f32x4  __attribute__((ext_vector_type(4)));

__device__ __forceinline__ unsigned short f2bf(float f) {
    unsigned u = __float_as_uint(f);
    u += 0x7FFF + ((u >> 16) & 1);          // round-to-nearest-even
    return (unsigned short)(u >> 16);
}
__device__ __forceinline__ float bf2f(unsigned short h) {
    return __uint_as_float(((unsigned)h) << 16);
}
// 3-term bf16 cascade: x = b0 + b1 + b2 + delta, |delta| <= 2^-27 |x|
__device__ __forceinline__ void split3(float x, unsigned short& b0,
                                       unsigned short& b1, unsigned short& b2) {
    b0 = f2bf(x);
    float r1 = x - bf2f(b0);                // exact (Sterbenz)
    b1 = f2bf(r1);
    float r2 = r1 - bf2f(b1);               // exact
    b2 = f2bf(r2);
}

// ---- kernel 1: split w into 3 bf16 planes in FRAGMENT-MAJOR order (same
// image as rounds 5/6): stage s, plane p, tile t, lane l holds
// w[t*16 + (l&15)][s*32 + (l>>4)*8 + j] at ws16[((s*24 + p*8 + t)*64 + l)*8].
__global__ __launch_bounds__(256) void presplit_w(
    const float* __restrict__ w, short* __restrict__ ws16)
{
    const int g = blockIdx.x * 256 + threadIdx.x;    // 65536 total
    const int l = g & 63;
    const int t = (g >> 6) & 7;
    const int s = g >> 9;                            // 0..127
    const int e  = t * 16 + (l & 15);
    const int kb = s * BK + ((l >> 4) & 3) * 8;
    const float* src = w + (size_t)e * HIDDEN + kb;
    float4 v0 = *(const float4*)(src);
    float4 v1 = *(const float4*)(src + 4);
    float vv[8] = {v0.x, v0.y, v0.z, v0.w, v1.x, v1.y, v1.z, v1.w};
    unsigned short h0[8], h1[8], h2[8];
#pragma unroll
    for (int j = 0; j < 8; ++j) split3(vv[j], h0[j], h1[j], h2[j]);
    const size_t base = ((size_t)s * 24 + t) * 64 + l;
    bf16x8 o0 = {(short)h0[0],(short)h0[1],(short)h0[2],(short)h0[3],
                 (short)h0[4],(short)h0[5],(short)h0[6],(short)h0[7]};
    bf16x8 o1 = {(short)h1[0],(short)h1[1],(short)h1[2],(short)h1[3],
                 (short)h1[4],(short)h1[5],(short)h1[6],(short)h1[7]};
    bf16x8 o2 = {(short)h2[0],(short)h2[1],(short)h2[2],(short)h2[3],
                 (short)h2[4],(short)h2[5],(short)h2[6],(short)h2[7]};
    *(bf16x8*)(ws16 + (base + 0 * 8 * 64) * 8) = o0;
    *(bf16x8*)(ws16 + (base + 1 * 8 * 64) * 8) = o1;
    *(bf16x8*)(ws16 + (base + 2 * 8 * 64) * 8) = o2;
}

// 512 threads = 8 waves; wave owns 32 tokens x 32 experts (2x2 of 16x16).
// Grid 512 blocks -> 2 blocks/CU -> 16 waves/CU (50% occupancy ceiling),
// double round 6's 8 waves/CU: TLP to hide the per-stage barrier drains.
__global__ __launch_bounds__(512, 4) void glm4_router_mfma(
    const float* __restrict__ x, const short* __restrict__ wsplit,
    const float* __restrict__ bias, float* __restrict__ out)
{
    __shared__ __align__(16) short lds[LDS_SHORTS];

    const int tid  = threadIdx.x;
    const int wid  = tid >> 6;
    const int lane = tid & 63;
    const int rt_base = (wid & 1) * 2;      // row-tile base: 0 or 2
    const int ct_base = (wid >> 1) * 2;     // col-tile base: 0,2,4,6
    const int tok_base = blockIdx.x * TM;

    // A staging identity: thread -> (row, quad of 4 floats)
    const int arow = tid >> 3;              // 0..63
    const int aq   = tid & 7;               // 0..7
    const float* xrow = x + (size_t)(tok_base + arow) * HIDDEN + aq * 4;
    // fragment-major A write offset (shorts, plane 0)
    const int awr = ((arow >> 4) * 64 + ((arow & 15) | ((aq >> 1) << 4))) * 8
                    + (aq & 1) * 4;

    f32x4 acc[2][2];        // all 6 split-products, zeroed every K=128
    double accd[2][2][4];   // fp64 running sum
#pragma unroll
    for (int r = 0; r < 2; ++r)
#pragma unroll
        for (int c = 0; c < 2; ++c) {
            acc[r][c] = (f32x4){0.f, 0.f, 0.f, 0.f};
#pragma unroll
            for (int v = 0; v < 4; ++v) accd[r][c][v] = 0.0;
        }

    // prologue: stage-0 x
    float4 cx = *(const float4*)(xrow);

    for (int s = 0; s < NSTAGE; ++s) {
        if (s) __syncthreads();             // previous tile fully consumed

        // ---- B: 3 x 16B linear global_load_lds of the pre-split image ----
        {
            const char* gsrc = (const char*)wsplit + (size_t)s * B_CHUNK_BYTES + tid * 16;
            char* ldst = (char*)lds + B_BASE_SH * 2 + tid * 16;
#pragma unroll
            for (int i = 0; i < 3; ++i) {
                __builtin_amdgcn_global_load_lds(
                    (const __attribute__((address_space(1))) unsigned*)(gsrc + i * 8192),
                    (__attribute__((address_space(3))) unsigned*)(ldst + i * 8192),
                    16, 0, 0);
            }
        }

        // ---- prefetch next-stage x ----
        float4 nx = cx;
        if (s + 1 < NSTAGE) nx = *(const float4*)(xrow + (size_t)(s + 1) * BK);

        // ---- split current x (4 floats), write A fragments (b64, conflict-free) ----
        {
            float vv[4] = {cx.x, cx.y, cx.z, cx.w};
            unsigned short h0[4], h1[4], h2[4];
#pragma unroll
            for (int j = 0; j < 4; ++j) split3(vv[j], h0[j], h1[j], h2[j]);
            *(bf16x4*)(&lds[0 * A_PLANE_SH + awr]) =
                (bf16x4){(short)h0[0], (short)h0[1], (short)h0[2], (short)h0[3]};
            *(bf16x4*)(&lds[1 * A_PLANE_SH + awr]) =
                (bf16x4){(short)h1[0], (short)h1[1], (short)h1[2], (short)h1[3]};
            *(bf16x4*)(&lds[2 * A_PLANE_SH + awr]) =
                (bf16x4){(short)h2[0], (short)h2[1], (short)h2[2], (short)h2[3]};
        }
        __syncthreads();

        // ---- compute: 2x2 tile-pairs x 6 split-products = 24 MFMA ----
        {
            bf16x8 A[3][2], B[3][2];
#pragma unroll
            for (int p = 0; p < 3; ++p)
#pragma unroll
                for (int r = 0; r < 2; ++r)
                    A[p][r] = *(const bf16x8*)(
                        &lds[p * A_PLANE_SH + ((rt_base + r) * 64 + lane) * 8]);
#pragma unroll
            for (int p = 0; p < 3; ++p)
#pragma unroll
                for (int c = 0; c < 2; ++c)
                    B[p][c] = *(const bf16x8*)(
                        &lds[B_BASE_SH + p * B_PLANE_SH + ((ct_base + c) * 64 + lane) * 8]);
#pragma unroll
            for (int r = 0; r < 2; ++r)
#pragma unroll
                for (int c = 0; c < 2; ++c) {
                    acc[r][c] = __builtin_amdgcn_mfma_f32_16x16x32_bf16(A[0][r], B[0][c], acc[r][c], 0, 0, 0);
                    acc[r][c] = __builtin_amdgcn_mfma_f32_16x16x32_bf16(A[0][r], B[1][c], acc[r][c], 0, 0, 0);
                    acc[r][c] = __builtin_amdgcn_mfma_f32_16x16x32_bf16(A[1][r], B[0][c], acc[r][c], 0, 0, 0);
                    acc[r][c] = __builtin_amdgcn_mfma_f32_16x16x32_bf16(A[0][r], B[2][c], acc[r][c], 0, 0, 0);
                    acc[r][c] = __builtin_amdgcn_mfma_f32_16x16x32_bf16(A[2][r], B[0][c], acc[r][c], 0, 0, 0);
                    acc[r][c] = __builtin_amdgcn_mfma_f32_16x16x32_bf16(A[1][r], B[1][c], acc[r][c], 0, 0, 0);
                }
        }

        // ---- fold into fp64 every K=128 (caps fp32 C-accum random walk) ----
        if ((s & 3) == 3) {
#pragma unroll
            for (int r = 0; r < 2; ++r)
#pragma unroll
                for (int c = 0; c < 2; ++c) {
#pragma unroll
                    for (int v = 0; v < 4; ++v) accd[r][c][v] += (double)acc[r][c][v];
                    acc[r][c] = (f32x4){0.f, 0.f, 0.f, 0.f};
                }
        }
        cx = nx;
    }

    // ---- epilogue: logits -> biased scores into LDS overlay (fp32) ----
    __syncthreads();
    float* sc = (float*)lds;                       // [64][129] = 33 KB
#pragma unroll
    for (int r = 0; r < 2; ++r)
#pragma unroll
        for (int c = 0; c < 2; ++c) {
#pragma unroll
            for (int v = 0; v < 4; ++v) {
                const int tokl = (rt_base + r) * 16 + (lane >> 4) * 4 + v;
                const int e    = (ct_base + c) * 16 + (lane & 15);
                const float lg = (float)accd[r][c][v];
                const float sg = (float)(1.0 / (1.0 + exp(-(double)lg)));
                sc[tokl * SC_STRIDE + e] = sg + bias[e];
            }
        }
    __syncthreads();

    // ---- routing: one lane per token (wave 0) — verified logic ----
    if (tid < TM) {
        const float* scp = sc + tid * SC_STRIDE;

        float gsc[8];
#pragma unroll
        for (int g = 0; g < 8; ++g) {
            float m1 = -1e30f, m2 = -1e30f;
#pragma unroll
            for (int j = 0; j < 16; ++j) {
                const float v = scp[g * 16 + j];
                if (v > m1) { m2 = m1; m1 = v; }
                else if (v > m2) { m2 = v; }
            }
            gsc[g] = m1 + m2;
        }

        unsigned gmask = 0;
#pragma unroll
        for (int p = 0; p < 4; ++p) {
            float best = -1e30f; int bi = 0;
#pragma unroll
            for (int g = 0; g < 8; ++g) {
                const bool taken = (gmask >> g) & 1u;
                if (!taken && gsc[g] > best) { best = gsc[g]; bi = g; }
            }
            gmask |= 1u << bi;
        }

        unsigned long long chosen0 = 0ull, chosen1 = 0ull;
        int   idxs[8];
        float wts[8];
#pragma unroll
        for (int p = 0; p < 8; ++p) {
            float best = -1e30f; int bi = 0;
            for (int e = 0; e < NEXP; ++e) {
                const bool sel = (gmask >> (e >> 4)) & 1u;
                const float v = sel ? scp[e] : 0.0f;
                const bool ch = (e < 64) ? ((chosen0 >> e) & 1ull)
                                         : ((chosen1 >> (e - 64)) & 1ull);
                if (!ch && v > best) { best = v; bi = e; }
            }
            if (bi < 64) chosen0 |= 1ull << bi; else chosen1 |= 1ull << (bi - 64);
            idxs[p] = bi;
            // raw sigmoid recovered: (s + b) - b; error ~1e-7, far below the
            // weight tolerance we pass with (selection uses sc unchanged)
            wts[p] = scp[bi] - bias[bi];
        }

        float denom = 0.0f;
#pragma unroll
        for (int p = 0; p < 8; ++p) denom += wts[p];
        denom += 1e-20f;

        const size_t row = (size_t)(tok_base + tid) * 8;
        float* outI = out;
        float* outW = out + (size_t)T_TOKENS * 8;
#pragma unroll
        for (int p = 0; p < 8; ++p) {
            outI[row + p] = (float)idxs[p];
            outW[row + p] = wts[p] / denom;
        }
    }
}

extern "C" void kernel_launch(void* const* d_in, const int* in_sizes, int n_in,
                              void* d_out, int out_size, void* d_ws, size_t ws_size,
                              hipStream_t stream) {
    const float* x    = (const float*)d_in[0];  // [32768, 4096]
    const float* w    = (const float*)d_in[1];  // [128, 4096]
    const float* bias = (const float*)d_in[2];  // [128]
    float* out = (float*)d_out;                 // [idx-as-float | weights]
    short* ws16 = (short*)d_ws;                 // 3 MiB pre-split w image

    presplit_w<<<dim3(NSTAGE * 8 * 64 / 256), 256, 0, stream>>>(w, ws16);
    glm4_router_mfma<<<dim3(T_TOKENS / TM), 512, 0, stream>>>(x, ws16, bias, out);
}

// Round 9
// 282.261 us; speedup vs baseline: 3.4494x; 1.0123x over previous
//
#include <hip/hip_runtime.h>
#include <math.h>

#define T_TOKENS 32768
#define HIDDEN   4096
#define NEXP     128
#define TM       64
#define BK       32
#define NSTAGE   (HIDDEN / BK)            // 128

// LDS layout (bytes): [Abuf0 12K][Abuf1 12K][Bbuf0 24K][Bbuf1 24K] = 72 KiB
#define A_BUF_SH      6144                // shorts per A buffer
#define B_BASE_SH     (2 * A_BUF_SH)      // 12288
#define B_BUF_SH      12288               // shorts per B buffer
#define LDS_SHORTS    (B_BASE_SH + 2 * B_BUF_SH)   // 36864 shorts = 72 KiB
#define B_BASE_BYTES  (B_BASE_SH * 2)
#define B_BUF_BYTES   (B_BUF_SH * 2)      // 24576
#define A_PLANE_SH    2048
#define B_PLANE_SH    4096
#define SC_STRIDE     129
#define B_CHUNK_BYTES B_BUF_BYTES
#define WS_BYTES ((size_t)NSTAGE * B_CHUNK_BYTES)  // 3 MiB

typedef short bf16x8 __attribute__((ext_vector_type(8)));
typedef short bf16x4 __attribute__((ext_vector_type(4)));
typedef float f32x4  __attribute__((ext_vector_type(4)));

__device__ __forceinline__ unsigned short f2bf(float f) {
    unsigned u = __float_as_uint(f);
    u += 0x7FFF + ((u >> 16) & 1);          // round-to-nearest-even
    return (unsigned short)(u >> 16);
}
__device__ __forceinline__ float bf2f(unsigned short h) {
    return __uint_as_float(((unsigned)h) << 16);
}
// 3-term bf16 cascade: x = b0 + b1 + b2 + delta, |delta| <= 2^-27 |x|
__device__ __forceinline__ void split3(float x, unsigned short& b0,
                                       unsigned short& b1, unsigned short& b2) {
    b0 = f2bf(x);
    float r1 = x - bf2f(b0);                // exact (Sterbenz)
    b1 = f2bf(r1);
    float r2 = r1 - bf2f(b1);               // exact
    b2 = f2bf(r2);
}

// ---- kernel 1: split w into 3 bf16 planes, fragment-major (identical image
// to rounds 5-7): stage s, plane p, tile t, lane l holds
// w[t*16+(l&15)][s*32+(l>>4)*8+j] at ws16[((s*24 + p*8 + t)*64 + l)*8].
__global__ __launch_bounds__(256) void presplit_w(
    const float* __restrict__ w, short* __restrict__ ws16)
{
    const int g = blockIdx.x * 256 + threadIdx.x;    // 65536 total
    const int l = g & 63;
    const int t = (g >> 6) & 7;
    const int s = g >> 9;                            // 0..127
    const int e  = t * 16 + (l & 15);
    const int kb = s * BK + ((l >> 4) & 3) * 8;
    const float* src = w + (size_t)e * HIDDEN + kb;
    float4 v0 = *(const float4*)(src);
    float4 v1 = *(const float4*)(src + 4);
    float vv[8] = {v0.x, v0.y, v0.z, v0.w, v1.x, v1.y, v1.z, v1.w};
    unsigned short h0[8], h1[8], h2[8];
#pragma unroll
    for (int j = 0; j < 8; ++j) split3(vv[j], h0[j], h1[j], h2[j]);
    const size_t base = ((size_t)s * 24 + t) * 64 + l;
    bf16x8 o0 = {(short)h0[0],(short)h0[1],(short)h0[2],(short)h0[3],
                 (short)h0[4],(short)h0[5],(short)h0[6],(short)h0[7]};
    bf16x8 o1 = {(short)h1[0],(short)h1[1],(short)h1[2],(short)h1[3],
                 (short)h1[4],(short)h1[5],(short)h1[6],(short)h1[7]};
    bf16x8 o2 = {(short)h2[0],(short)h2[1],(short)h2[2],(short)h2[3],
                 (short)h2[4],(short)h2[5],(short)h2[6],(short)h2[7]};
    *(bf16x8*)(ws16 + (base + 0 * 8 * 64) * 8) = o0;
    *(bf16x8*)(ws16 + (base + 1 * 8 * 64) * 8) = o1;
    *(bf16x8*)(ws16 + (base + 2 * 8 * 64) * 8) = o2;
}

// 512 threads = 8 waves; wave owns 32 tok x 32 exp (2x2 of 16x16 tiles).
// Verified 2-phase pipeline (guide T3-minimum): stage buf^1 for s+1, compute
// buf for s, then ONE __syncthreads() (vmcnt(0)+lgkmcnt(0)+s_barrier) —
// the per-wave vmcnt drain happens BEFORE the barrier, giving the
// cross-wave visibility guarantee round 8 lacked.
__global__ __launch_bounds__(512, 4) void glm4_router_mfma(
    const float* __restrict__ x, const short* __restrict__ wsplit,
    const float* __restrict__ bias, float* __restrict__ out)
{
    __shared__ __align__(16) short lds[LDS_SHORTS];

    const int tid  = threadIdx.x;
    const int wid  = tid >> 6;
    const int lane = tid & 63;
    const int rt_base = (wid & 1) * 2;      // row-tile base: 0 or 2
    const int ct_base = (wid >> 1) * 2;     // col-tile base: 0,2,4,6
    const int tok_base = blockIdx.x * TM;

    // A staging: thread tid b64-writes shorts [tid*4..tid*4+3] of each plane
    // (contiguous across the wave -> 2-way banks = free). Fragment image
    // requires this thread to hold x[row][k] with t=tid>>7, l=(tid>>1)&63,
    // j4=(tid&1)*4: row = t*16+(l&15), k = s*32 + ((l>>4)&3)*8 + j4.
    const int al = (tid >> 1) & 63;
    const int at = tid >> 7;
    const int arow = at * 16 + (al & 15);
    const int akoff = ((al >> 4) & 3) * 8 + (tid & 1) * 4;
    const float* xsrc = x + (size_t)(tok_base + arow) * HIDDEN + akoff;
    const int awr = tid * 4;                // shorts, within a plane

    f32x4 acc[2][2];        // all 6 split-products, zeroed every K=128
    double accd[2][2][4];   // fp64 running sum
#pragma unroll
    for (int r = 0; r < 2; ++r)
#pragma unroll
        for (int c = 0; c < 2; ++c) {
            acc[r][c] = (f32x4){0.f, 0.f, 0.f, 0.f};
#pragma unroll
            for (int v = 0; v < 4; ++v) accd[r][c][v] = 0.0;
        }

    // helper macros ------------------------------------------------------
#define GLDS_B(S, BUF) do {                                                    \
    const char* gsrc_ = (const char*)wsplit + (size_t)(S) * B_CHUNK_BYTES + tid * 16; \
    char* ldst_ = (char*)lds + B_BASE_BYTES + (BUF) * B_BUF_BYTES + tid * 16;  \
    __builtin_amdgcn_global_load_lds(                                          \
        (const __attribute__((address_space(1))) unsigned*)(gsrc_),            \
        (__attribute__((address_space(3))) unsigned*)(ldst_), 16, 0, 0);       \
    __builtin_amdgcn_global_load_lds(                                          \
        (const __attribute__((address_space(1))) unsigned*)(gsrc_ + 8192),     \
        (__attribute__((address_space(3))) unsigned*)(ldst_ + 8192), 16, 0, 0);\
    __builtin_amdgcn_global_load_lds(                                          \
        (const __attribute__((address_space(1))) unsigned*)(gsrc_ + 16384),    \
        (__attribute__((address_space(3))) unsigned*)(ldst_ + 16384), 16, 0, 0);\
} while (0)

#define SPLIT_A(XV, BUF) do {                                                  \
    unsigned short h0_[4], h1_[4], h2_[4];                                     \
    split3((XV).x, h0_[0], h1_[0], h2_[0]);                                    \
    split3((XV).y, h0_[1], h1_[1], h2_[1]);                                    \
    split3((XV).z, h0_[2], h1_[2], h2_[2]);                                    \
    split3((XV).w, h0_[3], h1_[3], h2_[3]);                                    \
    short* ab_ = &lds[(BUF) * A_BUF_SH + awr];                                 \
    *(bf16x4*)(ab_ + 0 * A_PLANE_SH) =                                         \
        (bf16x4){(short)h0_[0], (short)h0_[1], (short)h0_[2], (short)h0_[3]};  \
    *(bf16x4*)(ab_ + 1 * A_PLANE_SH) =                                         \
        (bf16x4){(short)h1_[0], (short)h1_[1], (short)h1_[2], (short)h1_[3]};  \
    *(bf16x4*)(ab_ + 2 * A_PLANE_SH) =                                         \
        (bf16x4){(short)h2_[0], (short)h2_[1], (short)h2_[2], (short)h2_[3]};  \
} while (0)

#define COMPUTE(S, BUF) do {                                                   \
    bf16x8 Af[3][2], Bf[3][2];                                                 \
    _Pragma("unroll")                                                          \
    for (int p = 0; p < 3; ++p) {                                              \
        _Pragma("unroll")                                                      \
        for (int r = 0; r < 2; ++r)                                            \
            Af[p][r] = *(const bf16x8*)(&lds[(BUF) * A_BUF_SH + p * A_PLANE_SH \
                                             + ((rt_base + r) * 64 + lane) * 8]); \
        _Pragma("unroll")                                                      \
        for (int c = 0; c < 2; ++c)                                            \
            Bf[p][c] = *(const bf16x8*)(&lds[B_BASE_SH + (BUF) * B_BUF_SH      \
                                             + p * B_PLANE_SH                  \
                                             + ((ct_base + c) * 64 + lane) * 8]); \
    }                                                                          \
    _Pragma("unroll")                                                          \
    for (int r = 0; r < 2; ++r) {                                              \
        _Pragma("unroll")                                                      \
        for (int c = 0; c < 2; ++c) {                                          \
            acc[r][c] = __builtin_amdgcn_mfma_f32_16x16x32_bf16(Af[0][r], Bf[0][c], acc[r][c], 0, 0, 0); \
            acc[r][c] = __builtin_amdgcn_mfma_f32_16x16x32_bf16(Af[0][r], Bf[1][c], acc[r][c], 0, 0, 0); \
            acc[r][c] = __builtin_amdgcn_mfma_f32_16x16x32_bf16(Af[1][r], Bf[0][c], acc[r][c], 0, 0, 0); \
            acc[r][c] = __builtin_amdgcn_mfma_f32_16x16x32_bf16(Af[0][r], Bf[2][c], acc[r][c], 0, 0, 0); \
            acc[r][c] = __builtin_amdgcn_mfma_f32_16x16x32_bf16(Af[2][r], Bf[0][c], acc[r][c], 0, 0, 0); \
            acc[r][c] = __builtin_amdgcn_mfma_f32_16x16x32_bf16(Af[1][r], Bf[1][c], acc[r][c], 0, 0, 0); \
        }                                                                      \
    }                                                                          \
    if (((S) & 3) == 3) {                                                      \
        _Pragma("unroll")                                                      \
        for (int r = 0; r < 2; ++r)                                            \
            _Pragma("unroll")                                                  \
            for (int c = 0; c < 2; ++c) {                                      \
                _Pragma("unroll")                                              \
                for (int v = 0; v < 4; ++v) accd[r][c][v] += (double)acc[r][c][v]; \
                acc[r][c] = (f32x4){0.f, 0.f, 0.f, 0.f};                       \
            }                                                                  \
    }                                                                          \
} while (0)
    // ---------------------------------------------------------------------

    // prologue: fill buf0 with stage 0 (B glds + A split), prefetch x[1]
    float4 xA, xB;
    {
        float4 x0v = *(const float4*)(xsrc);
        GLDS_B(0, 0);
        xA = *(const float4*)(xsrc + BK);   // x[1]
        SPLIT_A(x0v, 0);
    }
    __syncthreads();    // vmcnt(0)+lgkmcnt(0)+barrier: buf0 globally visible

    // body(s): stage s+1 into buf^1 (glds B, split x), prefetch x[s+2],
    // compute stage s from buf, then __syncthreads().
#define BODY(S, BUF, XC, XL) do {                                              \
    GLDS_B((S) + 1, (BUF) ^ 1);                                                \
    {                                                                          \
        int s2_ = (S) + 2; if (s2_ > NSTAGE - 1) s2_ = NSTAGE - 1;             \
        XL = *(const float4*)(xsrc + (size_t)s2_ * BK);                        \
    }                                                                          \
    SPLIT_A(XC, (BUF) ^ 1);                                                    \
    COMPUTE(S, BUF);                                                           \
    __syncthreads();                                                           \
} while (0)

    for (int s = 0; s < NSTAGE - 2; s += 2) {
        BODY(s, 0, xA, xB);
        BODY(s + 1, 1, xB, xA);
    }
    BODY(NSTAGE - 2, 0, xA, xB);
    // tail: stage 127 from buf1, no staging
    COMPUTE(NSTAGE - 1, 1);

    // ---- epilogue: logits -> biased scores into LDS overlay (fp32) ----
    __syncthreads();
    float* sc = (float*)lds;                       // [64][129] = 33 KB
#pragma unroll
    for (int r = 0; r < 2; ++r)
#pragma unroll
        for (int c = 0; c < 2; ++c) {
#pragma unroll
            for (int v = 0; v < 4; ++v) {
                const int tokl = (rt_base + r) * 16 + (lane >> 4) * 4 + v;
                const int e    = (ct_base + c) * 16 + (lane & 15);
                const float lg = (float)accd[r][c][v];
                const float sg = (float)(1.0 / (1.0 + exp(-(double)lg)));
                sc[tokl * SC_STRIDE + e] = sg + bias[e];
            }
        }
    __syncthreads();

    // ---- routing: one lane per token (wave 0) — verified logic ----
    if (tid < TM) {
        const float* scp = sc + tid * SC_STRIDE;

        float gsc[8];
#pragma unroll
        for (int g = 0; g < 8; ++g) {
            float m1 = -1e30f, m2 = -1e30f;
#pragma unroll
            for (int j = 0; j < 16; ++j) {
                const float v = scp[g * 16 + j];
                if (v > m1) { m2 = m1; m1 = v; }
                else if (v > m2) { m2 = v; }
            }
            gsc[g] = m1 + m2;
        }

        unsigned gmask = 0;
#pragma unroll
        for (int p = 0; p < 4; ++p) {
            float best = -1e30f; int bi = 0;
#pragma unroll
            for (int g = 0; g < 8; ++g) {
                const bool taken = (gmask >> g) & 1u;
                if (!taken && gsc[g] > best) { best = gsc[g]; bi = g; }
            }
            gmask |= 1u << bi;
        }

        unsigned long long chosen0 = 0ull, chosen1 = 0ull;
        int   idxs[8];
        float wts[8];
#pragma unroll
        for (int p = 0; p < 8; ++p) {
            float best = -1e30f; int bi = 0;
            for (int e = 0; e < NEXP; ++e) {
                const bool sel = (gmask >> (e >> 4)) & 1u;
                const float v = sel ? scp[e] : 0.0f;
                const bool ch = (e < 64) ? ((chosen0 >> e) & 1ull)
                                         : ((chosen1 >> (e - 64)) & 1ull);
                if (!ch && v > best) { best = v; bi = e; }
            }
            if (bi < 64) chosen0 |= 1ull << bi; else chosen1 |= 1ull << (bi - 64);
            idxs[p] = bi;
            wts[p] = scp[bi] - bias[bi];   // raw sigmoid, ~1e-7 error
        }

        float denom = 0.0f;
#pragma unroll
        for (int p = 0; p < 8; ++p) denom += wts[p];
        denom += 1e-20f;

        const size_t row = (size_t)(tok_base + tid) * 8;
        float* outI = out;
        float* outW = out + (size_t)T_TOKENS * 8;
#pragma unroll
        for (int p = 0; p < 8; ++p) {
            outI[row + p] = (float)idxs[p];
            outW[row + p] = wts[p] / denom;
        }
    }
}

extern "C" void kernel_launch(void* const* d_in, const int* in_sizes, int n_in,
                              void* d_out, int out_size, void* d_ws, size_t ws_size,
                              hipStream_t stream) {
    const float* x    = (const float*)d_in[0];  // [32768, 4096]
    const float* w    = (const float*)d_in[1];  // [128, 4096]
    const float* bias = (const float*)d_in[2];  // [128]
    float* out = (float*)d_out;                 // [idx-as-float | weights]
    short* ws16 = (short*)d_ws;                 // 3 MiB pre-split w image

    presplit_w<<<dim3(NSTAGE * 8 * 64 / 256), 256, 0, stream>>>(w, ws16);
    glm4_router_mfma<<<dim3(T_TOKENS / TM), 512, 0, stream>>>(x, ws16, bias, out);
}